// Round 3
// baseline (580.715 us; speedup 1.0000x reference)
//
#include <hip/hip_runtime.h>
#include <cmath>

// Problem dims
#define S 96
#define BB 32
#define II 64
#define H 256
#define ROWS (S*BB)         // 3072 independent (s,b) rows
#define R 16                // rows per block (all same b, s-chunk of 16)
#define NB (ROWS/R)         // 192 blocks
#define NT 512              // 8 waves per block, 2 per SIMD
#define PADK 264            // LDS row stride in fp16 elems (stride 132 dwords ≡ 4 mod 32: 2-way max on b128 reads)

// ws float layout: fx | cx | weight-fragment region (ushort)
#define FX_OFF 0
#define CX_OFF (ROWS*H)
#define WREP_OFF (2*ROWS*H)   // byte-offset 6291456, 16B aligned

typedef __attribute__((ext_vector_type(8))) _Float16 f16x8;  // 8 fp16 = 4 VGPRs
typedef __attribute__((ext_vector_type(4))) _Float16 f16x4;  // 8B, one ds_write_b64
typedef __attribute__((ext_vector_type(4))) float f32x4;
typedef unsigned short ushort_t;

__device__ inline ushort_t h2u(_Float16 h){ return __builtin_bit_cast(ushort_t, h); }

// ---------------- prep 1: input projections (fp32), recurrent biases folded in --
__global__ void proj_kernel(const float* __restrict__ x,
                            const float* __restrict__ W_fx, const float* __restrict__ b_fx,
                            const float* __restrict__ W_cx, const float* __restrict__ b_cx,
                            const float* __restrict__ b_fh, const float* __restrict__ b_ch,
                            float* __restrict__ fx, float* __restrict__ cx)
{
    const int row = blockIdx.x;
    const int k = threadIdx.x;
    __shared__ float xs[II];
    if (k < II) xs[k] = x[row*II + k];
    __syncthreads();
    const float4* wf = reinterpret_cast<const float4*>(W_fx + k*II);
    const float4* wc = reinterpret_cast<const float4*>(W_cx + k*II);
    float af = 0.f, ac = 0.f;
#pragma unroll
    for (int i = 0; i < II/4; ++i) {
        float4 a = wf[i];
        float4 b = wc[i];
        const float* xp = &xs[i*4];
        af = fmaf(a.x, xp[0], fmaf(a.y, xp[1], fmaf(a.z, xp[2], fmaf(a.w, xp[3], af))));
        ac = fmaf(b.x, xp[0], fmaf(b.y, xp[1], fmaf(b.z, xp[2], fmaf(b.w, xp[3], ac))));
    }
    fx[row*H + k] = af + b_fx[k] + b_fh[k];   // fold recurrent bias: zf = accF + fx
    cx[row*H + k] = ac + b_cx[k] + b_ch[k];   // fold recurrent bias: zc = accC + cx
}

// ---------------- prep 2: weights → fp16 in MFMA fragment order --
// Fragment element (lane,j) of tile (nt,kt) holds W[n][k] with
//   n = nt*16 + (lane&15), k = kt*32 + (lane>>4)*8 + j
// This layout serves as the A-operand of mfma(W, h, acc): A[m][k], m=lane&15.
// Region: Wf (fp16) | Wc (fp16), each 65536 ushort = 128 KB.
__global__ void repack_kernel(const float* __restrict__ Wf, const float* __restrict__ Wc,
                              ushort_t* __restrict__ wr)
{
    const int idx = blockIdx.x*256 + threadIdx.x;   // 0..65535
    const int n = idx >> 8, k = idx & 255;
    const int lane = (((k >> 3) & 3) << 4) | (n & 15);
    const int dst = ((((n >> 4)*8 + (k >> 5))*64) + lane)*8 + (k & 7);
    wr[dst]         = h2u((_Float16)Wf[n*H + k]);   // v_cvt_f16_f32, RNE
    wr[65536 + dst] = h2u((_Float16)Wc[n*H + k]);
}

// ---------------- main: transposed-MFMA recurrence, register-resident weights ----
// Block = (b, s-chunk): 16 rows, 512 threads = 8 waves (2/SIMD), 192 blocks.
// TRANSPOSED form: Z^T = W·h^T, i.e. mfma(A=weight frag, B=h frag, acc).
//  - h fragments (B-operand) are read once per wave per kt per half: fanout = 4
//    MFMAs per ds_read_b128 (2 col-tiles × 2 gates share it). LDS reads per
//    block-step: 128 b128 (was 256) — the round-2 per-CU LDS-pipe bottleneck.
//  - C-layout after transpose: lane owns (h-row m = lane&15, 4 CONSECUTIVE cols
//    q*4..q*4+3 of each tile) → hi/lo LDS writes are single ds_write_b64 each
//    (was 8 scattered b16), hseq/hfin/cfin are global_store_dwordx4, fx/cx are
//    float4 loads.
// Weights: 2 tiles × 2 gates × 8 kt × 4 VGPR = 128 VGPRs, resident all 96 steps.
// One raw s_barrier + lgkmcnt(0) per step; global stores never drained (vmcnt
// retires lazily under the next step's MFMA phase).
__global__ __launch_bounds__(NT, 2) void lstm_mfma_kernel(
    const float* __restrict__ fx, const float* __restrict__ cx,
    const ushort_t* __restrict__ wr,
    float* __restrict__ out)
{
    const int tid = threadIdx.x;
    const int w = tid >> 6, lane = tid & 63;
    const int m = lane & 15, q = lane >> 4;
    const int b = blockIdx.x & 31;
    const int s0 = (blockIdx.x >> 5) * R;

    __shared__ ushort_t hh[2][2][R][PADK];   // [buf][hi/lo][row][col]

    for (int i = tid; i < 2*2*R*PADK; i += NT) (&hh[0][0][0][0])[i] = 0;

    // persistent weight fragments: [tile][kt], 32 frags × 4 VGPR = 128 VGPRs
    f16x8 wF[2][8], wC[2][8];
#pragma unroll
    for (int ti = 0; ti < 2; ++ti)
#pragma unroll
        for (int kt = 0; kt < 8; ++kt) {
            const int fo = (((w*2 + ti)*8 + kt)*64 + lane)*8;
            wF[ti][kt] = *(const f16x8*)&wr[fo];
            wC[ti][kt] = *(const f16x8*)&wr[65536 + fo];
        }

    // per-tile column base: 4 consecutive cols per thread per tile
    int col0[2];
    col0[0] = (w*2)*16 + q*4;
    col0[1] = (w*2 + 1)*16 + q*4;

    const int row = s0 + m;                  // this thread's h-row
    f32x4 cxr[2], cst[2];
#pragma unroll
    for (int ti = 0; ti < 2; ++ti) {
        cxr[ti] = *(const f32x4*)&cx[(row*BB + b)*H + col0[ti]];
        cst[ti] = (f32x4){0.f, 0.f, 0.f, 0.f};
    }

    float* hseq = out;
    float* hfin = out + (size_t)S*ROWS*H;
    float* cfin = hfin + (size_t)ROWS*H;

    const float* fxp = fx + b*H;             // advance BB*H per step
    float* op[2];
#pragma unroll
    for (int ti = 0; ti < 2; ++ti)
        op[ti] = hseq + ((size_t)row*BB + b)*H + col0[ti];   // advance S*BB*H per t

    __syncthreads();

    f32x4 fxv[2] = { *(const f32x4*)&fxp[col0[0]], *(const f32x4*)&fxp[col0[1]] };

#define LSTM_STEP(P, IS_LAST) do { \
    f32x4 accF[2], accC[2]; \
    _Pragma("unroll") \
    for (int ti = 0; ti < 2; ++ti) { \
        accF[ti] = (f32x4){0.f,0.f,0.f,0.f}; \
        accC[ti] = (f32x4){0.f,0.f,0.f,0.f}; \
    } \
    _Pragma("unroll") \
    for (int kt = 0; kt < 8; ++kt) { \
        f16x8 aH = *(const f16x8*)&hh[P][0][m][kt*32 + q*8]; \
        f16x8 aL = *(const f16x8*)&hh[P][1][m][kt*32 + q*8]; \
        _Pragma("unroll") \
        for (int ti = 0; ti < 2; ++ti) { \
            accF[ti] = __builtin_amdgcn_mfma_f32_16x16x32_f16(wF[ti][kt], aH, accF[ti], 0, 0, 0); \
            accF[ti] = __builtin_amdgcn_mfma_f32_16x16x32_f16(wF[ti][kt], aL, accF[ti], 0, 0, 0); \
            accC[ti] = __builtin_amdgcn_mfma_f32_16x16x32_f16(wC[ti][kt], aH, accC[ti], 0, 0, 0); \
            accC[ti] = __builtin_amdgcn_mfma_f32_16x16x32_f16(wC[ti][kt], aL, accC[ti], 0, 0, 0); \
        } \
    } \
    fxp += BB*H;   /* prefetch t+1 BEFORE this step's stores */ \
    f32x4 fxn[2] = { *(const f32x4*)&fxp[col0[0]], *(const f32x4*)&fxp[col0[1]] }; \
    _Pragma("unroll") \
    for (int ti = 0; ti < 2; ++ti) { \
        f32x4 hnv, cnv; \
        _Pragma("unroll") \
        for (int j = 0; j < 4; ++j) { \
            const float zf = accF[ti][j] + fxv[ti][j]; \
            const float g  = 1.f/(1.f + __expf(-zf)); \
            const float zc = accC[ti][j] + cxr[ti][j]; \
            const float cand = 1.f - 2.f/(1.f + __expf(2.f*zc));   /* tanh */ \
            const float cn = g*(cst[ti][j] + cand); \
            cnv[j] = cn; \
            hnv[j] = g*(1.f - 2.f/(1.f + __expf(2.f*cn))); \
        } \
        cst[ti] = cnv; \
        *(f32x4*)op[ti] = hnv; op[ti] += (size_t)S*BB*H; \
        f16x4 hi4, lo4; \
        _Pragma("unroll") \
        for (int j = 0; j < 4; ++j) { \
            hi4[j] = (_Float16)hnv[j]; \
            lo4[j] = (_Float16)(hnv[j] - (float)hi4[j]); \
        } \
        *(f16x4*)&hh[(P)^1][0][m][col0[ti]] = hi4; \
        *(f16x4*)&hh[(P)^1][1][m][col0[ti]] = lo4; \
        if (IS_LAST) { \
            const size_t ro = ((size_t)row*BB + b)*H + col0[ti]; \
            *(f32x4*)&hfin[ro] = hnv; \
            *(f32x4*)&cfin[ro] = cnv; \
        } \
    } \
    fxv[0] = fxn[0]; fxv[1] = fxn[1]; \
    asm volatile("s_waitcnt lgkmcnt(0)" ::: "memory"); \
    __builtin_amdgcn_s_barrier(); \
    asm volatile("" ::: "memory"); \
} while (0)

    for (int t = 0; t < S-2; t += 2) {
        LSTM_STEP(0, 0);
        LSTM_STEP(1, 0);
    }
    LSTM_STEP(0, 0);
    LSTM_STEP(1, 1);

#undef LSTM_STEP
}

extern "C" void kernel_launch(void* const* d_in, const int* in_sizes, int n_in,
                              void* d_out, int out_size, void* d_ws, size_t ws_size,
                              hipStream_t stream)
{
    const float* x    = (const float*)d_in[0];
    const float* W_fx = (const float*)d_in[1];
    const float* b_fx = (const float*)d_in[2];
    const float* W_fh = (const float*)d_in[3];
    const float* b_fh = (const float*)d_in[4];
    const float* W_cx = (const float*)d_in[5];
    const float* b_cx = (const float*)d_in[6];
    const float* W_ch = (const float*)d_in[7];
    const float* b_ch = (const float*)d_in[8];
    float* out = (float*)d_out;
    float* ws  = (float*)d_ws;

    float* fx = ws + FX_OFF;
    float* cx = ws + CX_OFF;
    ushort_t* wrp = (ushort_t*)(ws + WREP_OFF);

    hipLaunchKernelGGL(proj_kernel, dim3(ROWS), dim3(H), 0, stream,
                       x, W_fx, b_fx, W_cx, b_cx, b_fh, b_ch, fx, cx);
    hipLaunchKernelGGL(repack_kernel, dim3(H*H/256), dim3(256), 0, stream,
                       W_fh, W_ch, wrp);
    hipLaunchKernelGGL(lstm_mfma_kernel, dim3(NB), dim3(NT), 0, stream,
                       fx, cx, wrp, out);
}

// Round 4
// 503.443 us; speedup vs baseline: 1.1535x; 1.1535x over previous
//
#include <hip/hip_runtime.h>
#include <cmath>

// Problem dims
#define S 96
#define BB 32
#define II 64
#define H 256
#define ROWS (S*BB)         // 3072 independent (s,b) rows
#define R 16                // rows per block (all same b, s-chunk of 16)
#define NB (ROWS/R)         // 192 blocks
#define NT 512              // 8 waves per block, 2 per SIMD
#define PADK 272            // LDS row stride in fp16 elems: 136 dwords = 8 mod 32 banks
                            // -> b128 fragment reads are 4-way (was 8-way at 264)

// ws float layout: fx | cx | weight-fragment region (ushort)
#define FX_OFF 0
#define CX_OFF (ROWS*H)
#define WREP_OFF (2*ROWS*H)   // byte-offset 6291456, 16B aligned

typedef __attribute__((ext_vector_type(8))) _Float16 f16x8;  // 8 fp16 = 4 VGPRs
typedef __attribute__((ext_vector_type(4))) _Float16 f16x4;  // 8B, one ds_write_b64
typedef __attribute__((ext_vector_type(4))) float f32x4;
typedef unsigned short ushort_t;

__device__ inline ushort_t h2u(_Float16 h){ return __builtin_bit_cast(ushort_t, h); }

// Fast transcendentals: raw v_rcp_f32 (1 ulp) instead of IEEE divide sequence.
__device__ inline float sigm_fast(float x){
    return __builtin_amdgcn_rcpf(1.f + __expf(-x));
}
__device__ inline float tanh_fast(float x){           // tanh(x) = 1 - 2/(1+e^{2x})
    return 1.f - 2.f*__builtin_amdgcn_rcpf(1.f + __expf(2.f*x));
}

// ---------------- prep 1: input projections (fp32), recurrent biases folded in --
__global__ void proj_kernel(const float* __restrict__ x,
                            const float* __restrict__ W_fx, const float* __restrict__ b_fx,
                            const float* __restrict__ W_cx, const float* __restrict__ b_cx,
                            const float* __restrict__ b_fh, const float* __restrict__ b_ch,
                            float* __restrict__ fx, float* __restrict__ cx)
{
    const int row = blockIdx.x;
    const int k = threadIdx.x;
    __shared__ float xs[II];
    if (k < II) xs[k] = x[row*II + k];
    __syncthreads();
    const float4* wf = reinterpret_cast<const float4*>(W_fx + k*II);
    const float4* wc = reinterpret_cast<const float4*>(W_cx + k*II);
    float af = 0.f, ac = 0.f;
#pragma unroll
    for (int i = 0; i < II/4; ++i) {
        float4 a = wf[i];
        float4 b = wc[i];
        const float* xp = &xs[i*4];
        af = fmaf(a.x, xp[0], fmaf(a.y, xp[1], fmaf(a.z, xp[2], fmaf(a.w, xp[3], af))));
        ac = fmaf(b.x, xp[0], fmaf(b.y, xp[1], fmaf(b.z, xp[2], fmaf(b.w, xp[3], ac))));
    }
    fx[row*H + k] = af + b_fx[k] + b_fh[k];   // fold recurrent bias: zf = accF + fx
    cx[row*H + k] = ac + b_cx[k] + b_ch[k];   // fold recurrent bias: zc = accC + cx
}

// ---------------- prep 2: weights → fp16 in MFMA fragment order --
// Fragment element (lane,j) of tile (nt,kt) holds W[n][k] with
//   n = nt*16 + (lane&15), k = kt*32 + (lane>>4)*8 + j
// This layout serves as the A-operand of mfma(W, h, acc): A[m][k], m=lane&15.
// Region: Wf (fp16) | Wc (fp16), each 65536 ushort = 128 KB.
__global__ void repack_kernel(const float* __restrict__ Wf, const float* __restrict__ Wc,
                              ushort_t* __restrict__ wr)
{
    const int idx = blockIdx.x*256 + threadIdx.x;   // 0..65535
    const int n = idx >> 8, k = idx & 255;
    const int lane = (((k >> 3) & 3) << 4) | (n & 15);
    const int dst = ((((n >> 4)*8 + (k >> 5))*64) + lane)*8 + (k & 7);
    wr[dst]         = h2u((_Float16)Wf[n*H + k]);   // v_cvt_f16_f32, RNE
    wr[65536 + dst] = h2u((_Float16)Wc[n*H + k]);
}

// ---------------- main: transposed-MFMA recurrence ----------------
// Block = (b, s-chunk): 16 rows, 512 threads = 8 waves (2/SIMD), 192 blocks.
// Z^T = W·h^T: mfma(A=weight frag, B=h frag, acc). Lane owns (h-row m = lane&15,
// 4 consecutive cols q*4..+3 of each 16-col tile).
// Step structure (round-4): MFMA(ti=0) → MFMA(ti=1, own ds_reads) →
// elementwise(ti=0) → elementwise(ti=1). ew(0) is independent of ti=1's MFMA
// chain, so the scheduler can interleave VALU with MFMA/lgkm stalls.
// All reciprocals are raw v_rcp_f32 (no IEEE div sequences).
__global__ __launch_bounds__(NT, 2) void lstm_mfma_kernel(
    const float* __restrict__ fx, const float* __restrict__ cx,
    const ushort_t* __restrict__ wr,
    float* __restrict__ out)
{
    const int tid = threadIdx.x;
    const int w = tid >> 6, lane = tid & 63;
    const int m = lane & 15, q = lane >> 4;
    const int b = blockIdx.x & 31;
    const int s0 = (blockIdx.x >> 5) * R;

    __shared__ ushort_t hh[2][2][R][PADK];   // [buf][hi/lo][row][col]

    for (int i = tid; i < 2*2*R*PADK; i += NT) (&hh[0][0][0][0])[i] = 0;

    // persistent weight fragments: [tile][kt], 32 frags × 4 VGPR = 128 VGPRs
    f16x8 wF[2][8], wC[2][8];
#pragma unroll
    for (int ti = 0; ti < 2; ++ti)
#pragma unroll
        for (int kt = 0; kt < 8; ++kt) {
            const int fo = (((w*2 + ti)*8 + kt)*64 + lane)*8;
            wF[ti][kt] = *(const f16x8*)&wr[fo];
            wC[ti][kt] = *(const f16x8*)&wr[65536 + fo];
        }

    // per-tile column base: 4 consecutive cols per thread per tile
    int col0[2];
    col0[0] = (w*2)*16 + q*4;
    col0[1] = (w*2 + 1)*16 + q*4;

    const int row = s0 + m;                  // this thread's h-row
    f32x4 cxr[2], cst[2];
#pragma unroll
    for (int ti = 0; ti < 2; ++ti) {
        cxr[ti] = *(const f32x4*)&cx[(row*BB + b)*H + col0[ti]];
        cst[ti] = (f32x4){0.f, 0.f, 0.f, 0.f};
    }

    float* hseq = out;
    float* hfin = out + (size_t)S*ROWS*H;
    float* cfin = hfin + (size_t)ROWS*H;

    const float* fxp = fx + b*H;             // advance BB*H per step
    float* op[2];
#pragma unroll
    for (int ti = 0; ti < 2; ++ti)
        op[ti] = hseq + ((size_t)row*BB + b)*H + col0[ti];   // advance S*BB*H per t

    __syncthreads();

    f32x4 fxv[2] = { *(const f32x4*)&fxp[col0[0]], *(const f32x4*)&fxp[col0[1]] };

// one gate-pair MFMA pass for tile ti (reads its own h fragments)
#define LSTM_MFMA_TI(P, ti, accFti, accCti) do { \
    _Pragma("unroll") \
    for (int kt = 0; kt < 8; ++kt) { \
        f16x8 aH = *(const f16x8*)&hh[P][0][m][kt*32 + q*8]; \
        f16x8 aL = *(const f16x8*)&hh[P][1][m][kt*32 + q*8]; \
        accFti = __builtin_amdgcn_mfma_f32_16x16x32_f16(wF[ti][kt], aH, accFti, 0, 0, 0); \
        accFti = __builtin_amdgcn_mfma_f32_16x16x32_f16(wF[ti][kt], aL, accFti, 0, 0, 0); \
        accCti = __builtin_amdgcn_mfma_f32_16x16x32_f16(wC[ti][kt], aH, accCti, 0, 0, 0); \
        accCti = __builtin_amdgcn_mfma_f32_16x16x32_f16(wC[ti][kt], aL, accCti, 0, 0, 0); \
    } \
} while (0)

// elementwise update + stores for tile ti
#define LSTM_EW_TI(P, ti, accFti, accCti, IS_LAST) do { \
    f32x4 hnv, cnv; \
    _Pragma("unroll") \
    for (int j = 0; j < 4; ++j) { \
        const float g    = sigm_fast(accFti[j] + fxv[ti][j]); \
        const float cand = tanh_fast(accCti[j] + cxr[ti][j]); \
        const float cn = g*(cst[ti][j] + cand); \
        cnv[j] = cn; \
        hnv[j] = g*tanh_fast(cn); \
    } \
    cst[ti] = cnv; \
    *(f32x4*)op[ti] = hnv; op[ti] += (size_t)S*BB*H; \
    f16x4 hi4, lo4; \
    _Pragma("unroll") \
    for (int j = 0; j < 4; ++j) { \
        hi4[j] = (_Float16)hnv[j]; \
        lo4[j] = (_Float16)(hnv[j] - (float)hi4[j]); \
    } \
    *(f16x4*)&hh[(P)^1][0][m][col0[ti]] = hi4; \
    *(f16x4*)&hh[(P)^1][1][m][col0[ti]] = lo4; \
    if (IS_LAST) { \
        const size_t ro = ((size_t)row*BB + b)*H + col0[ti]; \
        *(f32x4*)&hfin[ro] = hnv; \
        *(f32x4*)&cfin[ro] = cnv; \
    } \
} while (0)

#define LSTM_STEP(P, IS_LAST) do { \
    f32x4 accF0 = (f32x4){0.f,0.f,0.f,0.f}, accC0 = (f32x4){0.f,0.f,0.f,0.f}; \
    f32x4 accF1 = (f32x4){0.f,0.f,0.f,0.f}, accC1 = (f32x4){0.f,0.f,0.f,0.f}; \
    LSTM_MFMA_TI(P, 0, accF0, accC0); \
    LSTM_MFMA_TI(P, 1, accF1, accC1); \
    fxp += BB*H;   /* prefetch t+1 BEFORE this step's stores */ \
    f32x4 fxn0 = *(const f32x4*)&fxp[col0[0]]; \
    f32x4 fxn1 = *(const f32x4*)&fxp[col0[1]]; \
    LSTM_EW_TI(P, 0, accF0, accC0, IS_LAST);   /* can overlap ti=1 MFMA chain */ \
    LSTM_EW_TI(P, 1, accF1, accC1, IS_LAST); \
    fxv[0] = fxn0; fxv[1] = fxn1; \
    asm volatile("s_waitcnt lgkmcnt(0)" ::: "memory"); \
    __builtin_amdgcn_s_barrier(); \
    asm volatile("" ::: "memory"); \
} while (0)

    for (int t = 0; t < S-2; t += 2) {
        LSTM_STEP(0, 0);
        LSTM_STEP(1, 0);
    }
    LSTM_STEP(0, 0);
    LSTM_STEP(1, 1);

#undef LSTM_STEP
#undef LSTM_EW_TI
#undef LSTM_MFMA_TI
}

extern "C" void kernel_launch(void* const* d_in, const int* in_sizes, int n_in,
                              void* d_out, int out_size, void* d_ws, size_t ws_size,
                              hipStream_t stream)
{
    const float* x    = (const float*)d_in[0];
    const float* W_fx = (const float*)d_in[1];
    const float* b_fx = (const float*)d_in[2];
    const float* W_fh = (const float*)d_in[3];
    const float* b_fh = (const float*)d_in[4];
    const float* W_cx = (const float*)d_in[5];
    const float* b_cx = (const float*)d_in[6];
    const float* W_ch = (const float*)d_in[7];
    const float* b_ch = (const float*)d_in[8];
    float* out = (float*)d_out;
    float* ws  = (float*)d_ws;

    float* fx = ws + FX_OFF;
    float* cx = ws + CX_OFF;
    ushort_t* wrp = (ushort_t*)(ws + WREP_OFF);

    hipLaunchKernelGGL(proj_kernel, dim3(ROWS), dim3(H), 0, stream,
                       x, W_fx, b_fx, W_cx, b_cx, b_fh, b_ch, fx, cx);
    hipLaunchKernelGGL(repack_kernel, dim3(H*H/256), dim3(256), 0, stream,
                       W_fh, W_ch, wrp);
    hipLaunchKernelGGL(lstm_mfma_kernel, dim3(NB), dim3(NT), 0, stream,
                       fx, cx, wrp, out);
}

// Round 6
// 431.567 us; speedup vs baseline: 1.3456x; 1.1665x over previous
//
#include <hip/hip_runtime.h>
#include <cmath>

// Problem dims
#define S 96
#define BB 32
#define II 64
#define H 256
#define ROWS (S*BB)         // 3072 independent (s,b) rows
#define R 16                // rows per block (s-chunk of 16, same b)
#define NB (ROWS/R)         // 192 blocks
#define NT 1024             // 16 waves per block, 4 per SIMD
#define PADK 272            // LDS row stride in fp16 elems: 136 dwords = 8 mod 32 banks

// ws float layout: fx | cx | weight-fragment region (ushort)
#define FX_OFF 0
#define CX_OFF (ROWS*H)
#define WREP_OFF (2*ROWS*H)   // byte-offset 6291456, 16B aligned

typedef __attribute__((ext_vector_type(8))) _Float16 f16x8;  // 8 fp16 = 4 VGPRs
typedef __attribute__((ext_vector_type(4))) _Float16 f16x4;  // 8B, one ds_write_b64
typedef __attribute__((ext_vector_type(4))) float f32x4;
typedef unsigned short ushort_t;

__device__ inline ushort_t h2u(_Float16 h){ return __builtin_bit_cast(ushort_t, h); }

// Fast transcendentals: raw v_rcp_f32 (1 ulp) instead of IEEE divide sequence.
__device__ inline float sigm_fast(float x){
    return __builtin_amdgcn_rcpf(1.f + __expf(-x));
}
__device__ inline float tanh_fast(float x){           // tanh(x) = 1 - 2/(1+e^{2x})
    return 1.f - 2.f*__builtin_amdgcn_rcpf(1.f + __expf(2.f*x));
}

// ---------------- prep 1: input projections (fp32), recurrent biases folded in --
// 192 blocks × 16 rows: x-tile staged in LDS; each thread owns ONE output col k
// and reads its two W rows ONCE for all 16 rows (W traffic 1.6 GB -> 25 MB).
__global__ __launch_bounds__(H) void proj_kernel(
    const float* __restrict__ x,
    const float* __restrict__ W_fx, const float* __restrict__ b_fx,
    const float* __restrict__ W_cx, const float* __restrict__ b_cx,
    const float* __restrict__ b_fh, const float* __restrict__ b_ch,
    float* __restrict__ fx, float* __restrict__ cx)
{
    const int r0 = blockIdx.x * 16;          // first of 16 flat rows
    const int k  = threadIdx.x;              // output col 0..255

    __shared__ float xs[16][II];
    // 16*64 = 1024 floats = 256 float4 loads, one per thread
    {
        float4 v = reinterpret_cast<const float4*>(x + r0*II)[k];
        reinterpret_cast<float4*>(&xs[0][0])[k] = v;
    }
    __syncthreads();

    const float4* wf = reinterpret_cast<const float4*>(W_fx + k*II);
    const float4* wc = reinterpret_cast<const float4*>(W_cx + k*II);
    float af[16], ac[16];
#pragma unroll
    for (int r = 0; r < 16; ++r) { af[r] = 0.f; ac[r] = 0.f; }
#pragma unroll
    for (int i = 0; i < II/4; ++i) {
        const float4 a = wf[i];
        const float4 b = wc[i];
#pragma unroll
        for (int r = 0; r < 16; ++r) {
            const float* xp = &xs[r][i*4];
            af[r] = fmaf(a.x, xp[0], fmaf(a.y, xp[1], fmaf(a.z, xp[2], fmaf(a.w, xp[3], af[r]))));
            ac[r] = fmaf(b.x, xp[0], fmaf(b.y, xp[1], fmaf(b.z, xp[2], fmaf(b.w, xp[3], ac[r]))));
        }
    }
    const float bf = b_fx[k] + b_fh[k];
    const float bc = b_cx[k] + b_ch[k];
#pragma unroll
    for (int r = 0; r < 16; ++r) {
        fx[(r0 + r)*H + k] = af[r] + bf;     // coalesced across k
        cx[(r0 + r)*H + k] = ac[r] + bc;
    }
}

// ---------------- prep 2: weights → fp16 in MFMA fragment order --
// Fragment element (lane,j) of tile (nt,kt) holds W[n][k] with
//   n = nt*16 + (lane&15), k = kt*32 + (lane>>4)*8 + j
// Serves as A-operand of mfma(W, h, acc). Region: Wf | Wc, each 65536 ushort.
__global__ void repack_kernel(const float* __restrict__ Wf, const float* __restrict__ Wc,
                              ushort_t* __restrict__ wr)
{
    const int idx = blockIdx.x*256 + threadIdx.x;   // 0..65535
    const int n = idx >> 8, k = idx & 255;
    const int lane = (((k >> 3) & 3) << 4) | (n & 15);
    const int dst = ((((n >> 4)*8 + (k >> 5))*64) + lane)*8 + (k & 7);
    wr[dst]         = h2u((_Float16)Wf[n*H + k]);   // v_cvt_f16_f32, RNE
    wr[65536 + dst] = h2u((_Float16)Wc[n*H + k]);
}

// ---------------- main: transposed-MFMA recurrence ----------------
// Block = (b, s-chunk): 16 rows, 1024 threads = 16 waves (4/SIMD), 192 blocks.
// Z^T = W·h^T: mfma(A=weight frag, B=h frag, acc). Each wave owns ONE 16-col
// tile (nt = w) of BOTH gates: weights = 16 frags = 64 VGPR, register-resident.
// Lane owns (h-row m = lane&15, 4 consecutive cols q*4..+3).
// 4 waves/SIMD cover trans-pipe (8-cyc wave64 exp/rcp) and ds_read-latency
// bubbles that 2 waves could not — per-SIMD totals are unchanged vs R4, the
// win is TLP. fx/cx are folded into the MFMA accumulator init (C-layout owns
// exactly those 4 cols).
__global__ __launch_bounds__(NT, 4) void lstm_mfma_kernel(
    const float* __restrict__ fx, const float* __restrict__ cx,
    const ushort_t* __restrict__ wr,
    float* __restrict__ out)
{
    const int tid = threadIdx.x;
    const int w = tid >> 6, lane = tid & 63;
    const int m = lane & 15, q = lane >> 4;
    const int b = blockIdx.x & 31;
    const int s0 = (blockIdx.x >> 5) * R;

    __shared__ ushort_t hh[2][2][R][PADK];   // [buf][hi/lo][row][col]

    for (int i = tid; i < 2*2*R*PADK; i += NT) (&hh[0][0][0][0])[i] = 0;

    // persistent weight fragments for tile nt = w: 16 frags × 4 VGPR = 64 VGPRs
    f16x8 wF[8], wC[8];
#pragma unroll
    for (int kt = 0; kt < 8; ++kt) {
        const int fo = ((w*8 + kt)*64 + lane)*8;
        wF[kt] = *(const f16x8*)&wr[fo];
        wC[kt] = *(const f16x8*)&wr[65536 + fo];
    }

    const int col0 = w*16 + q*4;             // 4 consecutive cols per thread
    const int row  = s0 + m;                 // this thread's h-row

    f32x4 cxr = *(const f32x4*)&cx[(row*BB + b)*H + col0];
    f32x4 cst = (f32x4){0.f, 0.f, 0.f, 0.f};

    float* hseq = out;
    float* hfin = out + (size_t)S*ROWS*H;
    float* cfin = hfin + (size_t)ROWS*H;

    const float* fxp = fx + b*H + col0;      // advance BB*H per step
    float* op = hseq + ((size_t)row*BB + b)*H + col0;   // advance S*BB*H per t

    __syncthreads();

    f32x4 fxv = *(const f32x4*)fxp;

#define LSTM_STEP(P, IS_LAST) do { \
    f32x4 accF = fxv;      /* fold input projection into acc init */ \
    f32x4 accC = cxr;      /* fold (time-invariant) candidate projection */ \
    _Pragma("unroll") \
    for (int kt = 0; kt < 8; ++kt) { \
        f16x8 aH = *(const f16x8*)&hh[P][0][m][kt*32 + q*8]; \
        f16x8 aL = *(const f16x8*)&hh[P][1][m][kt*32 + q*8]; \
        accF = __builtin_amdgcn_mfma_f32_16x16x32_f16(wF[kt], aH, accF, 0, 0, 0); \
        accC = __builtin_amdgcn_mfma_f32_16x16x32_f16(wC[kt], aH, accC, 0, 0, 0); \
        accF = __builtin_amdgcn_mfma_f32_16x16x32_f16(wF[kt], aL, accF, 0, 0, 0); \
        accC = __builtin_amdgcn_mfma_f32_16x16x32_f16(wC[kt], aL, accC, 0, 0, 0); \
    } \
    fxp += BB*H;   /* prefetch t+1 BEFORE this step's stores */ \
    f32x4 fxn = *(const f32x4*)fxp; \
    f32x4 hnv, cnv; \
    _Pragma("unroll") \
    for (int j = 0; j < 4; ++j) { \
        const float g    = sigm_fast(accF[j]); \
        const float cand = tanh_fast(accC[j]); \
        const float cn = g*(cst[j] + cand); \
        cnv[j] = cn; \
        hnv[j] = g*tanh_fast(cn); \
    } \
    cst = cnv; \
    *(f32x4*)op = hnv; op += (size_t)S*BB*H; \
    f16x4 hi4, lo4; \
    _Pragma("unroll") \
    for (int j = 0; j < 4; ++j) { \
        hi4[j] = (_Float16)hnv[j]; \
        lo4[j] = (_Float16)(hnv[j] - (float)hi4[j]); \
    } \
    *(f16x4*)&hh[(P)^1][0][m][col0] = hi4; \
    *(f16x4*)&hh[(P)^1][1][m][col0] = lo4; \
    if (IS_LAST) { \
        const size_t ro = ((size_t)row*BB + b)*H + col0; \
        *(f32x4*)&hfin[ro] = hnv; \
        *(f32x4*)&cfin[ro] = cnv; \
    } \
    fxv = fxn; \
    asm volatile("s_waitcnt lgkmcnt(0)" ::: "memory"); \
    __builtin_amdgcn_s_barrier(); \
    asm volatile("" ::: "memory"); \
} while (0)

    for (int t = 0; t < S-2; t += 2) {
        LSTM_STEP(0, 0);
        LSTM_STEP(1, 0);
    }
    LSTM_STEP(0, 0);
    LSTM_STEP(1, 1);

#undef LSTM_STEP
}

extern "C" void kernel_launch(void* const* d_in, const int* in_sizes, int n_in,
                              void* d_out, int out_size, void* d_ws, size_t ws_size,
                              hipStream_t stream)
{
    const float* x    = (const float*)d_in[0];
    const float* W_fx = (const float*)d_in[1];
    const float* b_fx = (const float*)d_in[2];
    const float* W_fh = (const float*)d_in[3];
    const float* b_fh = (const float*)d_in[4];
    const float* W_cx = (const float*)d_in[5];
    const float* b_cx = (const float*)d_in[6];
    const float* W_ch = (const float*)d_in[7];
    const float* b_ch = (const float*)d_in[8];
    float* out = (float*)d_out;
    float* ws  = (float*)d_ws;

    float* fx = ws + FX_OFF;
    float* cx = ws + CX_OFF;
    ushort_t* wrp = (ushort_t*)(ws + WREP_OFF);

    hipLaunchKernelGGL(proj_kernel, dim3(NB), dim3(H), 0, stream,
                       x, W_fx, b_fx, W_cx, b_cx, b_fh, b_ch, fx, cx);
    hipLaunchKernelGGL(repack_kernel, dim3(H*H/256), dim3(256), 0, stream,
                       W_fh, W_ch, wrp);
    hipLaunchKernelGGL(lstm_mfma_kernel, dim3(NB), dim3(NT), 0, stream,
                       fx, cx, wrp, out);
}